// Round 1
// baseline (78.284 us; speedup 1.0000x reference)
//
#include <hip/hip_runtime.h>
#include <math.h>

// One fused kernel, one block of 256 threads.
// Work breakdown:
//   stage conv_w/conv_b -> conv (each thread: one of 16x16 positions, 4 out ch)
//   -> maxpool+linear partials (each thread: one of 256 pooled elems)
//   -> wave64 shuffle reduction -> thread0: 9 IK Newton steps
//   -> threads 0..18: trajectory points, thread 32: odometry pose.
__global__ __launch_bounds__(256) void robot_app_kernel(
    const float* __restrict__ x,       // [3,64,64]
    const float* __restrict__ pose0,   // [3]
    const float* __restrict__ angles0, // [2]
    const float* __restrict__ ticks,   // [2]
    const float* __restrict__ conv_w,  // [4,3,4,4] OIHW
    const float* __restrict__ conv_b,  // [4]
    const float* __restrict__ lin_w,   // [2,256]
    const float* __restrict__ lin_b,   // [2]
    float* __restrict__ out)           // [41] = traj[19][2] ++ pose[3]
{
    __shared__ float s_w[192];
    __shared__ float s_b[4];
    __shared__ float s_conv[4][16][16];
    __shared__ float s_red[2][4];
    __shared__ float s_pts[6];   // start.xy, mid.xy, end.xy

    const int tid = threadIdx.x;

    // stage conv weights/bias into LDS (broadcast reads later -> conflict-free)
    if (tid < 192) s_w[tid] = conv_w[tid];
    if (tid >= 192 && tid < 196) s_b[tid - 192] = conv_b[tid - 192];
    __syncthreads();

    // ---- Conv2d(3->4, k=4, s=4, p=1): each thread one (oh,ow) of 16x16 ----
    {
        const int oh = tid >> 4, ow = tid & 15;
        float acc0 = 0.f, acc1 = 0.f, acc2 = 0.f, acc3 = 0.f;
        #pragma unroll
        for (int ci = 0; ci < 3; ++ci) {
            #pragma unroll
            for (int kh = 0; kh < 4; ++kh) {
                const int ih = oh * 4 - 1 + kh;
                if (ih < 0 || ih >= 64) continue;   // zero padding
                #pragma unroll
                for (int kw = 0; kw < 4; ++kw) {
                    const int iw = ow * 4 - 1 + kw;
                    if (iw < 0 || iw >= 64) continue;
                    const float v = x[(ci * 64 + ih) * 64 + iw];
                    const int wb = (ci * 4 + kh) * 4 + kw;  // within [3][4][4] block
                    acc0 += v * s_w[0 * 48 + wb];
                    acc1 += v * s_w[1 * 48 + wb];
                    acc2 += v * s_w[2 * 48 + wb];
                    acc3 += v * s_w[3 * 48 + wb];
                }
            }
        }
        s_conv[0][oh][ow] = fmaxf(acc0 + s_b[0], 0.f);
        s_conv[1][oh][ow] = fmaxf(acc1 + s_b[1], 0.f);
        s_conv[2][oh][ow] = fmaxf(acc2 + s_b[2], 0.f);
        s_conv[3][oh][ow] = fmaxf(acc3 + s_b[3], 0.f);
    }
    __syncthreads();

    // ---- MaxPool2d(2,2) + Linear(256->2) partials ----
    // flatten index (channel-major): tid = c*64 + ph*8 + pw
    {
        const int c = tid >> 6, rem = tid & 63, ph = rem >> 3, pw = rem & 7;
        const float a = s_conv[c][2 * ph][2 * pw];
        const float b = s_conv[c][2 * ph][2 * pw + 1];
        const float d = s_conv[c][2 * ph + 1][2 * pw];
        const float e = s_conv[c][2 * ph + 1][2 * pw + 1];
        const float m = fmaxf(fmaxf(a, b), fmaxf(d, e));
        float v0 = m * lin_w[tid];
        float v1 = m * lin_w[256 + tid];
        #pragma unroll
        for (int off = 32; off >= 1; off >>= 1) {
            v0 += __shfl_down(v0, off, 64);
            v1 += __shfl_down(v1, off, 64);
        }
        if ((tid & 63) == 0) { s_red[0][tid >> 6] = v0; s_red[1][tid >> 6] = v1; }
    }
    __syncthreads();

    // ---- IK: 9 Newton steps (serial chain, thread 0) ----
    if (tid == 0) {
        const float t0 = s_red[0][0] + s_red[0][1] + s_red[0][2] + s_red[0][3] + lin_b[0];
        const float t1 = s_red[1][0] + s_red[1][1] + s_red[1][2] + s_red[1][3] + lin_b[1];
        float q1 = angles0[0], q2 = angles0[1];
        #pragma unroll
        for (int it = 0; it < 9; ++it) {
            const float s1 = sinf(q1), c1 = cosf(q1);
            const float s12 = sinf(q1 + q2), c12 = cosf(q1 + q2);
            const float px = c1 + c12, py = s1 + s12;     // L1 = L2 = 1
            const float e0 = t0 - px, e1 = t1 - py;
            const float j11 = -s1 - s12, j12 = -s12;
            const float j21 = c1 + c12,  j22 = c12;
            const float det = j11 * j22 - j12 * j21;
            const float inv_det = 1.0f / (det + 1e-6f);
            const float dq0 = (j22 * e0 - j12 * e1) * inv_det;
            const float dq1 = (-j21 * e0 + j11 * e1) * inv_det;
            q1 += dq0;   // ALPHA = 1
            q2 += dq1;
        }
        const float sx = cosf(q1) + cosf(q1 + q2);
        const float sy = sinf(q1) + sinf(q1 + q2);
        s_pts[0] = sx;          s_pts[1] = sy;           // start
        s_pts[2] = sx - 0.2f;   s_pts[3] = sy;           // mid = start + retract
        s_pts[4] = sx - 0.2f;   s_pts[5] = sy - 0.1f;    // end = mid + push
    }
    __syncthreads();

    // ---- trajectory (19 pts) + odometry ----
    if (tid < 19) {
        float ax, ay, bx, by, t;
        if (tid < 10) {         // seg1: start -> mid, t = i/9
            t = (float)tid / 9.0f;
            ax = s_pts[0]; ay = s_pts[1]; bx = s_pts[2]; by = s_pts[3];
        } else {                // seg2[1:]: mid -> end, t = (i-9)/9
            t = (float)(tid - 9) / 9.0f;
            ax = s_pts[2]; ay = s_pts[3]; bx = s_pts[4]; by = s_pts[5];
        }
        out[2 * tid]     = ax * (1.0f - t) + bx * t;
        out[2 * tid + 1] = ay * (1.0f - t) + by * t;
    } else if (tid == 32) {
        const float d_l = ticks[0] * 1e-4f;   // DIST_PER_TICK
        const float d_r = ticks[1] * 1e-4f;
        const float d_c = 0.5f * (d_l + d_r);
        const float d_th = (d_r - d_l) * 2.0f;   // / AXLE_WIDTH(0.5)
        const float avg = pose0[2] + 0.5f * d_th;
        out[38] = pose0[0] + d_c * cosf(avg);
        out[39] = pose0[1] + d_c * sinf(avg);
        out[40] = pose0[2] + d_th;
    }
}

extern "C" void kernel_launch(void* const* d_in, const int* in_sizes, int n_in,
                              void* d_out, int out_size, void* d_ws, size_t ws_size,
                              hipStream_t stream) {
    (void)in_sizes; (void)n_in; (void)out_size; (void)d_ws; (void)ws_size;
    robot_app_kernel<<<1, 256, 0, stream>>>(
        (const float*)d_in[0],   // sensor_input [1,3,64,64]
        (const float*)d_in[1],   // initial_pose [3]
        (const float*)d_in[2],   // initial_angles [2]
        (const float*)d_in[3],   // wheel_ticks [2]
        (const float*)d_in[4],   // conv_w [4,3,4,4]
        (const float*)d_in[5],   // conv_b [4]
        (const float*)d_in[6],   // lin_w [2,256]
        (const float*)d_in[7],   // lin_b [2]
        (float*)d_out);          // [41]
}